// Round 11
// baseline (658.997 us; speedup 1.0000x reference)
//
#include <hip/hip_runtime.h>

#define Bn 4
#define Sn 4096
#define Dn 1024
#define En 8
#define Cn 1024
#define Fn 2048
#define Mn (Bn * Cn) // 4096 rows per expert (all batches)

typedef __bf16 bf16x4 __attribute__((ext_vector_type(4)));
typedef __bf16 bf16x8 __attribute__((ext_vector_type(8)));
typedef float f32x4 __attribute__((ext_vector_type(4)));

// async global->LDS, 16B per lane, linear LDS dest (wave-uniform base + lane*16)
#define GLOAD16(gsrc, ldst)                                                    \
  __builtin_amdgcn_global_load_lds(                                            \
      (const __attribute__((address_space(1))) void*)(gsrc),                   \
      (__attribute__((address_space(3))) void*)(ldst), 16, 0, 0)

#define VMCNT4() asm volatile("s_waitcnt vmcnt(4)" ::: "memory")
#define VMCNT2() asm volatile("s_waitcnt vmcnt(2)" ::: "memory")
#define VMCNT0() asm volatile("s_waitcnt vmcnt(0)" ::: "memory")
#define SCHEDB() __builtin_amdgcn_sched_barrier(0)
#define SBAR() __builtin_amdgcn_s_barrier()
#define PRIO(p) __builtin_amdgcn_s_setprio(p)

// ---- transpose + cast: in[e][K][N] f32  ->  out[e][N][K] bf16 ----
__global__ __launch_bounds__(256) void tcast_kernel(
    const float* __restrict__ in, __bf16* __restrict__ out, int K, int N) {
  __shared__ float t[32][33];
  const int e = blockIdx.z;
  const float* src = in + (size_t)e * K * N;
  __bf16* dst = out + (size_t)e * K * N;
  const int n0 = blockIdx.x << 5, k0 = blockIdx.y << 5;
  const int tx = threadIdx.x & 31, ty = threadIdx.x >> 5;
#pragma unroll
  for (int i = 0; i < 4; ++i)
    t[ty + i * 8][tx] = src[(size_t)(k0 + ty + i * 8) * N + (n0 + tx)];
  __syncthreads();
#pragma unroll
  for (int i = 0; i < 4; ++i)
    dst[(size_t)(n0 + ty + i * 8) * K + (k0 + tx)] = (__bf16)t[tx][ty + i * 8];
}

// ---- gather + cast: Xg[e][m][d] = bf16(x[b(m)][tok[b,e,c(m)]][d]) ----
__global__ __launch_bounds__(256) void gather_cast_kernel(
    const float* __restrict__ x, const int* __restrict__ tok,
    __bf16* __restrict__ Xg) {
  const int gid = blockIdx.x * 4 + (threadIdx.x >> 6); // row in [0, En*Mn)
  const int lane = threadIdx.x & 63;
  const int e = gid >> 12, m = gid & 4095, b = m >> 10, c = m & 1023;
  const int t = tok[((size_t)b * En + e) * Cn + c];
  const float* src = x + ((size_t)b * Sn + t) * Dn;
  __bf16* dst = Xg + (size_t)gid * Dn;
#pragma unroll
  for (int i = 0; i < 4; ++i) {
    f32x4 v = *(const f32x4*)(src + i * 256 + lane * 4);
    bf16x4 o;
    o[0] = (__bf16)v[0];
    o[1] = (__bf16)v[1];
    o[2] = (__bf16)v[2];
    o[3] = (__bf16)v[3];
    *(bf16x4*)(dst + i * 256 + lane * 4) = o;
  }
}

// ====== GEMM cores: 1024 thr / 16 waves (4x4), 256-row tile, 4-slot rot ======
// Slot = A 16KB [256 r x 64B] + B 16KB [256 vr x 64B] = 32KB; 4 slots = 128KB
// -> 1 block/CU, 4 waves/SIMD. Per-wave 64x64 out, acc[4][4].
// In-loop VALU minimized: slot base add + immediate-offset ds_reads.
// Per iter: vmcnt(4) [slot c landed; c+1,c+2 in flight]; s_barrier; 8 ds_read
// (imm offsets); stage((c+3)&3) [post-barrier: race-safe]; 16 MFMA (setprio).

// ==== fused dual GEMM (w1,w2) + SwiGLU(+ew) -> Hbh bf16 [4][Mn][Fn] ====
// Virtual B rows 0-127 = w1T panel (gate), 128-255 = w2T panel (value).
__global__ __launch_bounds__(1024, 4) void gemm12_kernel(
    const __bf16* __restrict__ Xg, const float* __restrict__ ew,
    const __bf16* __restrict__ w1T, const __bf16* __restrict__ w2T,
    __bf16* __restrict__ Hbh, int e0) {
  __shared__ __align__(16) char lds[131072];

  const int tid = threadIdx.x;
  const int lane = tid & 63, wid = tid >> 6;
  const int wr = wid >> 2, wc = wid & 3;
  const int mt = blockIdx.x, ft = blockIdx.y, eLoc = blockIdx.z;
  const int e = e0 + eLoc;

  const int srow = tid >> 2; // 0..255
  const int sof = ((tid & 3) ^ ((tid >> 3) & 3)) << 3; // pre-swizzled source
  const __bf16* pA = Xg + ((size_t)e * Mn + mt * 256 + srow) * Dn + sof;
  const __bf16* pB =
      (srow < 128)
          ? w1T + ((size_t)e * Fn + ft * 128 + srow) * Dn + sof
          : w2T + ((size_t)e * Fn + ft * 128 + (srow - 128)) * Dn + sof;

  auto stage = [&](int slot) {
    char* d = lds + (slot << 15) + tid * 16;
    GLOAD16(pA, d);
    GLOAD16(pB, d + 16384);
    pA += 32;
    pB += 32;
  };

  const int rl = lane & 15, kb = lane >> 4;
  const int swz = (kb ^ ((rl >> 1) & 3)) << 4; // 16B-block byte offset
  // loop-invariant fragment bases (slot 0)
  const char* aBase = lds + (wr * 64 + rl) * 64 + swz;
  const char* bBase = lds + 16384 + (wc * 64 + rl) * 64 + swz;

  f32x4 acc[4][4];
  const f32x4 z4 = {0.f, 0.f, 0.f, 0.f};
#pragma unroll
  for (int i = 0; i < 4; ++i)
#pragma unroll
    for (int j = 0; j < 4; ++j) acc[i][j] = z4;

  stage(0);
  stage(1);
  stage(2);

  const int KT = Dn / 32; // 32
#pragma unroll 1
  for (int c = 0; c < KT; ++c) {
    if (c + 2 < KT) VMCNT4();
    else if (c + 1 < KT) VMCNT2();
    else VMCNT0();
    SBAR();
    SCHEDB();
    const int so = (c & 3) << 15;
    const char* av = aBase + so;
    const char* bv = bBase + so;
    bf16x8 a4[4], b4[4];
#pragma unroll
    for (int f = 0; f < 4; ++f) {
      a4[f] = *(const bf16x8*)(av + f * 1024);
      b4[f] = *(const bf16x8*)(bv + f * 1024);
    }
    if (c + 3 < KT) stage((c + 3) & 3);
    PRIO(1);
#pragma unroll
    for (int fm = 0; fm < 4; ++fm)
#pragma unroll
      for (int fn = 0; fn < 4; ++fn)
        acc[fm][fn] = __builtin_amdgcn_mfma_f32_16x16x32_bf16(
            a4[fm], b4[fn], acc[fm][fn], 0, 0, 0);
    PRIO(0);
  }
  __syncthreads();

  // ---- epilogue: v-export -> in-place SwiGLU(+ew) -> coalesced store ----
  const int rl0 = (lane >> 4) << 2, cl = lane & 15;
  if (wc >= 2) { // value waves export v
    char* reg = lds + (wr * 2 + (wc - 2)) * 8192;
#pragma unroll
    for (int fm = 0; fm < 4; ++fm)
#pragma unroll
      for (int fn = 0; fn < 4; ++fn)
#pragma unroll
        for (int j = 0; j < 4; ++j) {
          const int row = fm * 16 + rl0 + j;
          *(__bf16*)(reg + row * 128 + ((fn ^ ((row >> 2) & 3)) << 5) +
                     cl * 2) = (__bf16)acc[fm][fn][j];
        }
  }
  __syncthreads();
  if (wc < 2) { // gate waves: h = silu(g)*v*ew, in place
    char* reg = lds + (wr * 2 + wc) * 8192;
    const int m0 = mt * 256 + wr * 64;
    const int b = m0 >> 10;
    const size_t ewBase = ((size_t)b * En + e) * Cn;
#pragma unroll
    for (int fm = 0; fm < 4; ++fm)
#pragma unroll
      for (int j = 0; j < 4; ++j) {
        const int row = fm * 16 + rl0 + j;
        const float wgt = ew[ewBase + ((m0 + row) & (Cn - 1))];
#pragma unroll
        for (int fn = 0; fn < 4; ++fn) {
          __bf16* p = (__bf16*)(reg + row * 128 +
                                ((fn ^ ((row >> 2) & 3)) << 5) + cl * 2);
          const float v = (float)*p;
          const float g = acc[fm][fn][j];
          *p = (__bf16)((g / (1.f + __expf(-g))) * v * wgt);
        }
      }
  }
  __syncthreads();
  // coalesced store: 256 rows x 128 cols bf16 = 64KB; 4 passes, 16B/lane
  __bf16* hBase = Hbh + ((size_t)eLoc * Mn + mt * 256) * Fn + ft * 128;
#pragma unroll
  for (int p = 0; p < 4; ++p) {
    const int row = p * 64 + (tid >> 4); // 0..255
    const int c8 = (tid & 15) * 8;       // 0..120
    const int region = ((row >> 6) << 1) + (c8 >> 6);
    const int rr = row & 63, cc = c8 & 63;
    bf16x8 v = *(const bf16x8*)(lds + region * 8192 + rr * 128 +
                                (((cc >> 4) ^ ((rr >> 2) & 3)) << 5) +
                                (cc & 15) * 2);
    *(bf16x8*)(hBase + (size_t)row * Fn + c8) = v;
  }
}

// ==== GEMM3: Hbh x w3T (256x256 tile) -> atomic scatter-add ====
__global__ __launch_bounds__(1024, 4) void gemm3_kernel(
    const __bf16* __restrict__ Hbh, const __bf16* __restrict__ w3T,
    const int* __restrict__ tok, float* __restrict__ out, int e0) {
  __shared__ __align__(16) char lds[131072];

  const int tid = threadIdx.x;
  const int lane = tid & 63, wid = tid >> 6;
  const int wr = wid >> 2, wc = wid & 3;
  const int mt = blockIdx.x, nt = blockIdx.y, eLoc = blockIdx.z;
  const int e = e0 + eLoc;

  const int srow = tid >> 2; // 0..255
  const int sof = ((tid & 3) ^ ((tid >> 3) & 3)) << 3;
  const __bf16* pA = Hbh + ((size_t)eLoc * Mn + mt * 256 + srow) * Fn + sof;
  const __bf16* pB = w3T + ((size_t)e * Dn + nt * 256 + srow) * Fn + sof;

  auto stage = [&](int slot) {
    char* d = lds + (slot << 15) + tid * 16;
    GLOAD16(pA, d);
    GLOAD16(pB, d + 16384);
    pA += 32;
    pB += 32;
  };

  const int rl = lane & 15, kb = lane >> 4;
  const int swz = (kb ^ ((rl >> 1) & 3)) << 4;
  const char* aBase = lds + (wr * 64 + rl) * 64 + swz;
  const char* bBase = lds + 16384 + (wc * 64 + rl) * 64 + swz;

  f32x4 acc[4][4];
  const f32x4 z4 = {0.f, 0.f, 0.f, 0.f};
#pragma unroll
  for (int i = 0; i < 4; ++i)
#pragma unroll
    for (int j = 0; j < 4; ++j) acc[i][j] = z4;

  stage(0);
  stage(1);
  stage(2);

  const int KT = Fn / 32; // 64
#pragma unroll 1
  for (int c = 0; c < KT; ++c) {
    if (c + 2 < KT) VMCNT4();
    else if (c + 1 < KT) VMCNT2();
    else VMCNT0();
    SBAR();
    SCHEDB();
    const int so = (c & 3) << 15;
    const char* av = aBase + so;
    const char* bv = bBase + so;
    bf16x8 a4[4], b4[4];
#pragma unroll
    for (int f = 0; f < 4; ++f) {
      a4[f] = *(const bf16x8*)(av + f * 1024);
      b4[f] = *(const bf16x8*)(bv + f * 1024);
    }
    if (c + 3 < KT) stage((c + 3) & 3);
    PRIO(1);
#pragma unroll
    for (int fm = 0; fm < 4; ++fm)
#pragma unroll
      for (int fn = 0; fn < 4; ++fn)
        acc[fm][fn] = __builtin_amdgcn_mfma_f32_16x16x32_bf16(
            a4[fm], b4[fn], acc[fm][fn], 0, 0, 0);
    PRIO(0);
  }

  // epilogue: atomic scatter-add into out[b, tok, :]
  const int m0 = mt * 256 + wr * 64;
  const int b = m0 >> 10;
  const int rl0 = (lane >> 4) << 2, cl = lane & 15;
  const int colBase = nt * 256 + wc * 64 + cl;
#pragma unroll
  for (int fm = 0; fm < 4; ++fm) {
#pragma unroll
    for (int j = 0; j < 4; ++j) {
      const int m = m0 + fm * 16 + rl0 + j;
      const int c2 = m & (Cn - 1);
      const int t = tok[((size_t)b * En + e) * Cn + c2];
      float* orow = out + ((size_t)b * Sn + t) * Dn + colBase;
#pragma unroll
      for (int fn = 0; fn < 4; ++fn)
        atomicAdd(orow + fn * 16, acc[fm][fn][j]);
    }
  }
}

extern "C" void kernel_launch(void* const* d_in, const int* in_sizes, int n_in,
                              void* d_out, int out_size, void* d_ws,
                              size_t ws_size, hipStream_t stream) {
  const float* x = (const float*)d_in[0];
  const float* ew = (const float*)d_in[1];
  const int* tok = (const int*)d_in[2];
  const float* w1 = (const float*)d_in[3];
  const float* w2 = (const float*)d_in[4];
  const float* w3 = (const float*)d_in[5];
  float* out = (float*)d_out;

  const size_t wE = (size_t)En * Dn * Fn;        // 16.78M elems per weight
  const size_t xgE = (size_t)En * Mn * Dn;       // 33.55M elems
  const size_t hbE = (size_t)(En / 2) * Mn * Fn; // 33.55M elems (half)
  __bf16* w1T = (__bf16*)d_ws;
  __bf16* w2T = w1T + wE;
  __bf16* w3T = w2T + wE;
  __bf16* Xg = w3T + wE;
  __bf16* Hbh = Xg + xgE;
  const size_t need = (3 * wE + xgE + hbE) * sizeof(__bf16); // ~235MB
  if (ws_size < need) return; // fail loudly (output stays poisoned)

  (void)hipMemsetAsync(d_out, 0, (size_t)Bn * Sn * Dn * sizeof(float), stream);

  tcast_kernel<<<dim3(Fn / 32, Dn / 32, En), 256, 0, stream>>>(w1, w1T, Dn, Fn);
  tcast_kernel<<<dim3(Fn / 32, Dn / 32, En), 256, 0, stream>>>(w2, w2T, Dn, Fn);
  tcast_kernel<<<dim3(Dn / 32, Fn / 32, En), 256, 0, stream>>>(w3, w3T, Fn, Dn);
  gather_cast_kernel<<<dim3(En * Mn / 4), 256, 0, stream>>>(x, tok, Xg);
  for (int h = 0; h < 2; ++h) {
    gemm12_kernel<<<dim3(16, 16, En / 2), 1024, 0, stream>>>(Xg, ew, w1T, w2T,
                                                             Hbh, h * (En / 2));
    gemm3_kernel<<<dim3(16, 4, En / 2), 1024, 0, stream>>>(Hbh, w3T, tok, out,
                                                           h * (En / 2));
  }
}

// Round 12
// 652.124 us; speedup vs baseline: 1.0105x; 1.0105x over previous
//
#include <hip/hip_runtime.h>

#define Bn 4
#define Sn 4096
#define Dn 1024
#define En 8
#define Cn 1024
#define Fn 2048
#define Mn (Bn * Cn) // 4096 rows per expert (all batches)

typedef __bf16 bf16x4 __attribute__((ext_vector_type(4)));
typedef __bf16 bf16x8 __attribute__((ext_vector_type(8)));
typedef float f32x4 __attribute__((ext_vector_type(4)));

// async global->LDS, 16B per lane, linear LDS dest (wave-uniform base + lane*16)
#define GLOAD16(gsrc, ldst)                                                    \
  __builtin_amdgcn_global_load_lds(                                            \
      (const __attribute__((address_space(1))) void*)(gsrc),                   \
      (__attribute__((address_space(3))) void*)(ldst), 16, 0, 0)

#define VMCNT3() asm volatile("s_waitcnt vmcnt(3)" ::: "memory")
#define VMCNT0() asm volatile("s_waitcnt vmcnt(0)" ::: "memory")
#define SCHEDB() __builtin_amdgcn_sched_barrier(0)
#define SBAR() __builtin_amdgcn_s_barrier()
#define PRIO(p) __builtin_amdgcn_s_setprio(p)

// ---- transpose + cast (w1 & w2 in one launch): [e][K][N] f32 -> [e][N][K] bf16
__global__ __launch_bounds__(256) void tcast12_kernel(
    const float* __restrict__ w1, const float* __restrict__ w2,
    __bf16* __restrict__ w1T, __bf16* __restrict__ w2T) {
  __shared__ float t[32][33];
  const int z = blockIdx.z; // 0..15: z<8 -> w1 expert z, else w2 expert z-8
  const int e = z & 7;
  const float* src = (z < 8 ? w1 : w2) + (size_t)e * Dn * Fn;
  __bf16* dst = (z < 8 ? w1T : w2T) + (size_t)e * Dn * Fn;
  const int n0 = blockIdx.x << 5, k0 = blockIdx.y << 5;
  const int tx = threadIdx.x & 31, ty = threadIdx.x >> 5;
#pragma unroll
  for (int i = 0; i < 4; ++i)
    t[ty + i * 8][tx] = src[(size_t)(k0 + ty + i * 8) * Fn + (n0 + tx)];
  __syncthreads();
#pragma unroll
  for (int i = 0; i < 4; ++i)
    dst[(size_t)(n0 + ty + i * 8) * Dn + (k0 + tx)] = (__bf16)t[tx][ty + i * 8];
}

// ---- transpose + cast: in[e][K][N] f32  ->  out[e][N][K] bf16 ----
__global__ __launch_bounds__(256) void tcast_kernel(
    const float* __restrict__ in, __bf16* __restrict__ out, int K, int N) {
  __shared__ float t[32][33];
  const int e = blockIdx.z;
  const float* src = in + (size_t)e * K * N;
  __bf16* dst = out + (size_t)e * K * N;
  const int n0 = blockIdx.x << 5, k0 = blockIdx.y << 5;
  const int tx = threadIdx.x & 31, ty = threadIdx.x >> 5;
#pragma unroll
  for (int i = 0; i < 4; ++i)
    t[ty + i * 8][tx] = src[(size_t)(k0 + ty + i * 8) * N + (n0 + tx)];
  __syncthreads();
#pragma unroll
  for (int i = 0; i < 4; ++i)
    dst[(size_t)(n0 + ty + i * 8) * K + (k0 + tx)] = (__bf16)t[tx][ty + i * 8];
}

// ---- gather + cast: Xg[e][m][d] = bf16(x[b(m)][tok[b,e,c(m)]][d]) ----
__global__ __launch_bounds__(256) void gather_cast_kernel(
    const float* __restrict__ x, const int* __restrict__ tok,
    __bf16* __restrict__ Xg) {
  const int gid = blockIdx.x * 4 + (threadIdx.x >> 6); // row in [0, En*Mn)
  const int lane = threadIdx.x & 63;
  const int e = gid >> 12, m = gid & 4095, b = m >> 10, c = m & 1023;
  const int t = tok[((size_t)b * En + e) * Cn + c];
  const float* src = x + ((size_t)b * Sn + t) * Dn;
  __bf16* dst = Xg + (size_t)gid * Dn;
#pragma unroll
  for (int i = 0; i < 4; ++i) {
    f32x4 v = *(const f32x4*)(src + i * 256 + lane * 4);
    bf16x4 o;
    o[0] = (__bf16)v[0];
    o[1] = (__bf16)v[1];
    o[2] = (__bf16)v[2];
    o[3] = (__bf16)v[3];
    *(bf16x4*)(dst + i * 256 + lane * 4) = o;
  }
}

// ========== GEMM cores (r9 verbatim = measured best: 653.6 us) ==========
// 72KB LDS = 3 slots x 24KB (A 8KB [128 r x 64B] + B 16KB [256 vr x 64B]).
// 512 thr / 8 waves (2 wr x 4 wc), 64x64 out per wave, single acc[4][4].
// Per iter: vmcnt(3) [slot c landed, slot c+1 in flight]; s_barrier; ds_reads
// slot c%3; issue stage((c+2)%3); MFMA. Slot (c+2)%3 was last read at iter
// c-1 (before every wave's barrier at iter c) -> overwrite is race-free.

// ==== fused dual GEMM (w1,w2) + SwiGLU(+ew) -> Hbh bf16 [4][Mn][Fn] ====
// Virtual B rows 0-127 = w1T panel (gate), 128-255 = w2T panel (value).
__global__ __launch_bounds__(512, 4) void gemm12_kernel(
    const __bf16* __restrict__ Xg, const float* __restrict__ ew,
    const __bf16* __restrict__ w1T, const __bf16* __restrict__ w2T,
    __bf16* __restrict__ Hbh, int e0) {
  __shared__ __align__(16) char lds[73728];

  const int tid = threadIdx.x;
  const int lane = tid & 63, wid = tid >> 6;
  const int wr = wid >> 2, wc = wid & 3;
  const int mt = blockIdx.x, ft = blockIdx.y, eLoc = blockIdx.z;
  const int e = e0 + eLoc;

  const int srow = tid >> 2;
  const int sof = ((tid & 3) ^ ((tid >> 3) & 3)) << 3; // pre-swizzled source
  const __bf16* pA = Xg + ((size_t)e * Mn + mt * 128 + srow) * Dn + sof;
  const __bf16* pB1 = w1T + ((size_t)e * Fn + ft * 128 + srow) * Dn + sof;
  const __bf16* pB2 = w2T + ((size_t)e * Fn + ft * 128 + srow) * Dn + sof;

  auto stage = [&](int slot) {
    char* d = lds + slot * 24576 + tid * 16;
    GLOAD16(pA, d);
    GLOAD16(pB1, d + 8192);
    GLOAD16(pB2, d + 16384);
    pA += 32;
    pB1 += 32;
    pB2 += 32;
  };

  const int rl = lane & 15, kb = lane >> 4;
  const int swz = (kb ^ ((rl >> 1) & 3)) << 4; // 16B-block byte offset

  f32x4 acc[4][4];
  const f32x4 z4 = {0.f, 0.f, 0.f, 0.f};
#pragma unroll
  for (int i = 0; i < 4; ++i)
#pragma unroll
    for (int j = 0; j < 4; ++j) acc[i][j] = z4;

  stage(0);
  stage(1);

  const int KT = Dn / 32; // 32
#pragma unroll 1
  for (int c = 0; c < KT; ++c) {
    if (c < KT - 1) VMCNT3();
    else VMCNT0();
    SBAR();
    SCHEDB();
    const char* Ab = lds + (c % 3) * 24576;
    const char* Bb = Ab + 8192;
    bf16x8 a4[4], b4[4];
#pragma unroll
    for (int f = 0; f < 4; ++f) {
      const int ra = wr * 64 + f * 16 + rl;
      a4[f] = *(const bf16x8*)(Ab + ra * 64 + swz);
      const int rb = wc * 64 + f * 16 + rl; // virtual B row 0..255
      b4[f] = *(const bf16x8*)(Bb + rb * 64 + swz);
    }
    if (c + 2 < KT) stage((c + 2) % 3);
    PRIO(1);
#pragma unroll
    for (int fm = 0; fm < 4; ++fm)
#pragma unroll
      for (int fn = 0; fn < 4; ++fn)
        acc[fm][fn] = __builtin_amdgcn_mfma_f32_16x16x32_bf16(
            a4[fm], b4[fn], acc[fm][fn], 0, 0, 0);
    PRIO(0);
  }
  __syncthreads();

  // ---- epilogue: v-export -> in-place SwiGLU(+ew) -> coalesced store ----
  const int rl0 = (lane >> 4) << 2, cl = lane & 15;
  if (wc >= 2) { // value waves export v
    char* reg = lds + (wr * 2 + (wc - 2)) * 8192;
#pragma unroll
    for (int fm = 0; fm < 4; ++fm)
#pragma unroll
      for (int fn = 0; fn < 4; ++fn)
#pragma unroll
        for (int j = 0; j < 4; ++j) {
          const int row = fm * 16 + rl0 + j;
          *(__bf16*)(reg + row * 128 + ((fn ^ ((row >> 2) & 3)) << 5) +
                     cl * 2) = (__bf16)acc[fm][fn][j];
        }
  }
  __syncthreads();
  if (wc < 2) { // gate waves: h = silu(g)*v*ew, in place
    char* reg = lds + (wr * 2 + wc) * 8192;
    const int m0 = mt * 128 + wr * 64;
    const int b = m0 >> 10;
    const size_t ewBase = ((size_t)b * En + e) * Cn;
#pragma unroll
    for (int fm = 0; fm < 4; ++fm)
#pragma unroll
      for (int j = 0; j < 4; ++j) {
        const int row = fm * 16 + rl0 + j;
        const float wgt = ew[ewBase + ((m0 + row) & (Cn - 1))];
#pragma unroll
        for (int fn = 0; fn < 4; ++fn) {
          __bf16* p = (__bf16*)(reg + row * 128 +
                                ((fn ^ ((row >> 2) & 3)) << 5) + cl * 2);
          const float v = (float)*p;
          const float g = acc[fm][fn][j];
          *p = (__bf16)((g / (1.f + __expf(-g))) * v * wgt);
        }
      }
  }
  __syncthreads();
  // coalesced store: 4 passes, 32 rows/pass, 16B per lane
  __bf16* hBase = Hbh + ((size_t)eLoc * Mn + mt * 128) * Fn + ft * 128;
#pragma unroll
  for (int p = 0; p < 4; ++p) {
    const int row = p * 32 + (tid >> 4);
    const int c8 = (tid & 15) * 8;
    const int reg = (row >> 6) * 2 + (c8 >> 6);
    const int rr = row & 63, cc = c8 & 63;
    bf16x8 v = *(const bf16x8*)(lds + reg * 8192 + rr * 128 +
                                (((cc >> 4) ^ ((rr >> 2) & 3)) << 5) +
                                (cc & 15) * 2);
    *(bf16x8*)(hBase + (size_t)row * Fn + c8) = v;
  }
}

// ==== GEMM3: Hbh x w3T (128x256 tile) -> atomic scatter-add ====
__global__ __launch_bounds__(512, 4) void gemm3_kernel(
    const __bf16* __restrict__ Hbh, const __bf16* __restrict__ w3T,
    const int* __restrict__ tok, float* __restrict__ out, int e0) {
  __shared__ __align__(16) char lds[73728];

  const int tid = threadIdx.x;
  const int lane = tid & 63, wid = tid >> 6;
  const int wr = wid >> 2, wc = wid & 3;
  const int mt = blockIdx.x, nt = blockIdx.y, eLoc = blockIdx.z;
  const int e = e0 + eLoc;

  const int srow = tid >> 2;
  const int sof = ((tid & 3) ^ ((tid >> 3) & 3)) << 3;
  const __bf16* pA = Hbh + ((size_t)eLoc * Mn + mt * 128 + srow) * Fn + sof;
  const __bf16* pB0 = w3T + ((size_t)e * Dn + nt * 256 + srow) * Fn + sof;
  const __bf16* pB1 = pB0 + (size_t)128 * Fn;

  auto stage = [&](int slot) {
    char* d = lds + slot * 24576 + tid * 16;
    GLOAD16(pA, d);
    GLOAD16(pB0, d + 8192);
    GLOAD16(pB1, d + 16384);
    pA += 32;
    pB0 += 32;
    pB1 += 32;
  };

  const int rl = lane & 15, kb = lane >> 4;
  const int swz = (kb ^ ((rl >> 1) & 3)) << 4;

  f32x4 acc[4][4];
  const f32x4 z4 = {0.f, 0.f, 0.f, 0.f};
#pragma unroll
  for (int i = 0; i < 4; ++i)
#pragma unroll
    for (int j = 0; j < 4; ++j) acc[i][j] = z4;

  stage(0);
  stage(1);

  const int KT = Fn / 32; // 64
#pragma unroll 1
  for (int c = 0; c < KT; ++c) {
    if (c < KT - 1) VMCNT3();
    else VMCNT0();
    SBAR();
    SCHEDB();
    const char* Ab = lds + (c % 3) * 24576;
    const char* Bb = Ab + 8192;
    bf16x8 a4[4], b4[4];
#pragma unroll
    for (int f = 0; f < 4; ++f) {
      const int ra = wr * 64 + f * 16 + rl;
      a4[f] = *(const bf16x8*)(Ab + ra * 64 + swz);
      const int rb = wc * 64 + f * 16 + rl; // 0..255
      b4[f] = *(const bf16x8*)(Bb + rb * 64 + swz);
    }
    if (c + 2 < KT) stage((c + 2) % 3);
    PRIO(1);
#pragma unroll
    for (int fm = 0; fm < 4; ++fm)
#pragma unroll
      for (int fn = 0; fn < 4; ++fn)
        acc[fm][fn] = __builtin_amdgcn_mfma_f32_16x16x32_bf16(
            a4[fm], b4[fn], acc[fm][fn], 0, 0, 0);
    PRIO(0);
  }

  // epilogue: atomic scatter-add into out[b, tok, :]
  const int m0 = mt * 128 + wr * 64;
  const int b = m0 >> 10;
  const int rl0 = (lane >> 4) << 2, cl = lane & 15;
  const int colBase = nt * 256 + wc * 64 + cl;
#pragma unroll
  for (int fm = 0; fm < 4; ++fm) {
#pragma unroll
    for (int j = 0; j < 4; ++j) {
      const int m = m0 + fm * 16 + rl0 + j;
      const int c2 = m & (Cn - 1);
      const int t = tok[((size_t)b * En + e) * Cn + c2];
      float* orow = out + ((size_t)b * Sn + t) * Dn + colBase;
#pragma unroll
      for (int fn = 0; fn < 4; ++fn)
        atomicAdd(orow + fn * 16, acc[fm][fn][j]);
    }
  }
}

extern "C" void kernel_launch(void* const* d_in, const int* in_sizes, int n_in,
                              void* d_out, int out_size, void* d_ws,
                              size_t ws_size, hipStream_t stream) {
  const float* x = (const float*)d_in[0];
  const float* ew = (const float*)d_in[1];
  const int* tok = (const int*)d_in[2];
  const float* w1 = (const float*)d_in[3];
  const float* w2 = (const float*)d_in[4];
  const float* w3 = (const float*)d_in[5];
  float* out = (float*)d_out;

  const size_t wE = (size_t)En * Dn * Fn;        // 16.78M elems per weight
  const size_t xgE = (size_t)En * Mn * Dn;       // 33.55M elems
  const size_t hbE = (size_t)(En / 2) * Mn * Fn; // 33.55M elems (half)
  __bf16* w1T = (__bf16*)d_ws;
  __bf16* w2T = w1T + wE;
  __bf16* w3T = w2T + wE;
  __bf16* Xg = w3T + wE;
  __bf16* Hbh = Xg + xgE;
  const size_t need = (3 * wE + xgE + hbE) * sizeof(__bf16); // ~235MB
  if (ws_size < need) return; // fail loudly (output stays poisoned)

  (void)hipMemsetAsync(d_out, 0, (size_t)Bn * Sn * Dn * sizeof(float), stream);

  tcast12_kernel<<<dim3(Fn / 32, Dn / 32, 2 * En), 256, 0, stream>>>(w1, w2,
                                                                     w1T, w2T);
  tcast_kernel<<<dim3(Dn / 32, Fn / 32, En), 256, 0, stream>>>(w3, w3T, Fn, Dn);
  gather_cast_kernel<<<dim3(En * Mn / 4), 256, 0, stream>>>(x, tok, Xg);
  for (int h = 0; h < 2; ++h) {
    gemm12_kernel<<<dim3(32, 16, En / 2), 512, 0, stream>>>(Xg, ew, w1T, w2T,
                                                            Hbh, h * (En / 2));
    gemm3_kernel<<<dim3(32, 4, En / 2), 512, 0, stream>>>(Hbh, w3T, tok, out,
                                                          h * (En / 2));
  }
}